// Round 4
// baseline (387.123 us; speedup 1.0000x reference)
//
#include <hip/hip_runtime.h>
#include <hip/hip_bf16.h>
#include <stdint.h>

// RWKV TimeMixing: N=8, T=2048, C=1024.
// Round 4: LDS-repack epilogues (coalesced dwordx4 stores), fused prep dispatch,
// 64x32 scan chunking (in-place prefix combine), L2-friendly block swizzle.

typedef float f4 __attribute__((ext_vector_type(4)));
typedef short bh8 __attribute__((ext_vector_type(8)));
typedef unsigned int u32;
typedef unsigned short u16;

__device__ __forceinline__ u32 cvt2bf(float a, float b) {
    __hip_bfloat162 h = __float22bfloat162_rn(make_float2(a, b));
    u32 u; __builtin_memcpy(&u, &h, 4); return u;
}
__device__ __forceinline__ float b2f(u16 u) {
    u32 x = (u32)u << 16; float f; __builtin_memcpy(&f, &x, 4); return f;
}
__device__ __forceinline__ u16 f2b(float f) {
    __hip_bfloat16 h = __float2bfloat16(f);
    u16 u; __builtin_memcpy(&u, &h, 2); return u;
}
__device__ __forceinline__ void gld_lds16(const void* g, void* l) {
    __builtin_amdgcn_global_load_lds(
        (const __attribute__((address_space(1))) u32*)g,
        (__attribute__((address_space(3))) u32*)l, 16, 0, 0);
}

// ---------------- shared GEMM mainloop: acc += A(m0:128,:) @ B(n0:128,:)^T, K=1024, BK=32 ----
// global_load_lds w16; global-source XOR swizzle (chunk c of row r -> slot c ^ ((r>>1)&3)),
// proven 0-conflict in R2/R3.
__device__ __forceinline__ void gemm_core(
    const u16* __restrict__ A, const u16* __restrict__ B,
    int m0, int n0, u16* As, u16* Bs, f4 (&acc)[4][4])
{
    const int tid  = threadIdx.x;
    const int w    = tid >> 6;
    const int lane = tid & 63;

    const int srow = w * 32 + (lane >> 2);
    const int slot = lane & 3;
    const int chk  = slot ^ ((srow >> 1) & 3);
    const u16* gA0 = A + (size_t)(m0 + srow) * 1024 + chk * 8;
    const u16* gA1 = gA0 + (size_t)16 * 1024;
    const u16* gB0 = B + (size_t)(n0 + srow) * 1024 + chk * 8;
    const u16* gB1 = gB0 + (size_t)16 * 1024;
    u16* lA0 = As + (w * 32) * 32;
    u16* lA1 = lA0 + 16 * 32;
    u16* lB0 = Bs + (w * 32) * 32;
    u16* lB1 = lB0 + 16 * 32;

    const int fr   = lane & 15;
    const int quad = lane >> 4;
    const int wm = (w & 1) * 64;
    const int wn = (w >> 1) * 64;
    const int sp = quad ^ ((fr >> 1) & 3);
    const int aoff = (wm + fr) * 32 + sp * 8;
    const int boff = (wn + fr) * 32 + sp * 8;

    for (int kk = 0; kk < 1024; kk += 32) {
        gld_lds16(gA0 + kk, lA0);
        gld_lds16(gA1 + kk, lA1);
        gld_lds16(gB0 + kk, lB0);
        gld_lds16(gB1 + kk, lB1);
        __syncthreads();
        bh8 af[4], bf[4];
#pragma unroll
        for (int i = 0; i < 4; i++) af[i] = *(const bh8*)(As + aoff + i * 16 * 32);
#pragma unroll
        for (int j = 0; j < 4; j++) bf[j] = *(const bh8*)(Bs + boff + j * 16 * 32);
#pragma unroll
        for (int i = 0; i < 4; i++)
#pragma unroll
            for (int j = 0; j < 4; j++)
                acc[i][j] = __builtin_amdgcn_mfma_f32_16x16x32_bf16(af[i], bf[j], acc[i][j], 0, 0, 0);
        __syncthreads();
    }
}

// Merged K/V/R GEMM. grid (24, 128): bx -> (proj, n0) [fastest => B panels reused across m via L2/L3],
// by -> m0. Epilogue: +bias, optional sigmoid, LDS repack -> dwordx4 bf16 stores.
__global__ __launch_bounds__(256, 4) void gemm_kvr(
    const u16* __restrict__ A, const u16* __restrict__ Wall, const float* __restrict__ bias,
    u16* __restrict__ Kb, u16* __restrict__ Vb, u16* __restrict__ SRb)
{
    __shared__ __align__(16) char pool[33792];   // K-loop: As(8K)+Bs(8K); epilogue: 128x132 u16
    u16* As = (u16*)pool;
    u16* Bs = (u16*)(pool + 8192);

    const int proj = blockIdx.x >> 3;
    const int n0 = (blockIdx.x & 7) * 128;
    const int m0 = blockIdx.y * 128;
    const u16* B = Wall + (size_t)proj * 1048576;

    f4 acc[4][4];
#pragma unroll
    for (int i = 0; i < 4; i++)
#pragma unroll
        for (int j = 0; j < 4; j++) { f4 z = {0.f, 0.f, 0.f, 0.f}; acc[i][j] = z; }
    gemm_core(A, B, m0, n0, As, Bs, acc);

    u16* Y = proj == 0 ? Kb : (proj == 1 ? Vb : SRb);
    const int lane = threadIdx.x & 63;
    const int w = threadIdx.x >> 6;
    const int fr = lane & 15, quad = lane >> 4;
    const int wm = (w & 1) * 64, wn = (w >> 1) * 64;
    const int rb = quad * 4;
    const int batch = m0 >> 11;
    float bv[4];
#pragma unroll
    for (int j = 0; j < 4; j++) bv[j] = bias[proj * 8192 + batch * 1024 + n0 + wn + j * 16 + fr];

    u16* S = (u16*)pool;                         // 128 rows x stride 132 u16
#pragma unroll
    for (int i = 0; i < 4; i++)
#pragma unroll
        for (int j = 0; j < 4; j++)
#pragma unroll
            for (int r = 0; r < 4; r++) {
                float v = acc[i][j][r] + bv[j];
                if (proj == 2) v = __fdividef(1.0f, 1.0f + __expf(-v));
                int row = wm + i * 16 + rb + r;
                int col = wn + j * 16 + fr;
                S[row * 132 + col] = f2b(v);
            }
    __syncthreads();
    const int ch = lane & 15;
#pragma unroll
    for (int t = 0; t < 8; t++) {
        int lrow = w * 32 + t * 4 + (lane >> 4);
        const u16* p = S + lrow * 132 + ch * 8;
        uint2 lo = *(const uint2*)p;             // byte addr: lrow*264 + ch*16, 8B-aligned
        uint2 hi = *(const uint2*)(p + 4);
        uint4 val = make_uint4(lo.x, lo.y, hi.x, hi.y);
        *(uint4*)(Y + (size_t)(m0 + lrow) * 1024 + n0 + ch * 8) = val;
    }
}

// Output GEMM: out(16384,1024) f32 = P @ Wo^T. grid (8, 128). 4-pass f32 LDS repack epilogue.
__global__ __launch_bounds__(256, 4) void gemm_out(
    const u16* __restrict__ A, const u16* __restrict__ B, float* __restrict__ Y)
{
    __shared__ __align__(16) char pool[33792];
    u16* As = (u16*)pool;
    u16* Bs = (u16*)(pool + 8192);
    const int n0 = blockIdx.x * 128;
    const int m0 = blockIdx.y * 128;
    f4 acc[4][4];
#pragma unroll
    for (int i = 0; i < 4; i++)
#pragma unroll
        for (int j = 0; j < 4; j++) { f4 z = {0.f, 0.f, 0.f, 0.f}; acc[i][j] = z; }
    gemm_core(A, B, m0, n0, As, Bs, acc);

    const int lane = threadIdx.x & 63;
    const int w = threadIdx.x >> 6;
    const int fr = lane & 15, quad = lane >> 4;
    const int wn = (w >> 1) * 64;
    const int rb = quad * 4;
    float* Sf = (float*)pool;                    // 32 rows x stride 132 f32 per pass (16.9 KB)
#pragma unroll
    for (int i = 0; i < 4; i++) {
        __syncthreads();                         // prior pass reads (or K-loop) complete
#pragma unroll
        for (int j = 0; j < 4; j++)
#pragma unroll
            for (int r = 0; r < 4; r++) {
                int lrow = (w & 1) * 16 + rb + r;
                Sf[lrow * 132 + wn + j * 16 + fr] = acc[i][j][r];
            }
        __syncthreads();
#pragma unroll
        for (int t = 0; t < 4; t++) {
            int lrow = w * 8 + t * 2 + (lane >> 5);
            int ch = lane & 31;
            f4 val = *(const f4*)(Sf + lrow * 132 + ch * 4);   // byte: lrow*528 + ch*16, 16B-aligned
            int g = m0 + ((lrow >> 4) << 6) + i * 16 + (lrow & 15);
            *(f4*)(Y + (size_t)g * 1024 + n0 + ch * 4) = val;
        }
    }
}

// ---------------- fused prep: convx | prepw | bias3, grid-partitioned ----------------
__global__ __launch_bounds__(256) void prep_all(
    const float* __restrict__ x, const float* __restrict__ lastx,
    const float* __restrict__ Wk, const float* __restrict__ Wv,
    const float* __restrict__ Wr, const float* __restrict__ Wo,
    const float* __restrict__ tmk, const float* __restrict__ tmv, const float* __restrict__ tmr,
    u16* __restrict__ xb, u16* __restrict__ Wall, float* __restrict__ bias)
{
    int b = blockIdx.x;
    if (b < 16384) {                              // convx: x f32 -> bf16
        int e = (b * 256 + threadIdx.x) << 2;
        f4 v = *(const f4*)(x + e);
        *(uint2*)(xb + e) = make_uint2(cvt2bf(v.x, v.y), cvt2bf(v.z, v.w));
    } else if (b < 20480) {                       // prepw: Wall[p] = bf16(mix_p * Wp), Wall[3]=bf16(Wo)
        int e = ((b - 16384) * 256 + threadIdx.x) << 2;
        int wid = e >> 20;
        int off = e & 1048575;
        int c = e & 1023;
        const float* src = wid == 0 ? Wk : (wid == 1 ? Wv : (wid == 2 ? Wr : Wo));
        f4 v = *(const f4*)(src + off);
        if (wid < 3) {
            const float* m = wid == 0 ? tmk : (wid == 1 ? tmv : tmr);
            v = v * *(const f4*)(m + c);
        }
        *(uint2*)(Wall + e) = make_uint2(cvt2bf(v.x, v.y), cvt2bf(v.z, v.w));
    } else {                                      // bias3: bias[p][b][n] = lastx[b,:].((1-m_p).Wp[n,:])
        int wid = (b - 20480) * 4 + (threadIdx.x >> 6);
        int lane = threadIdx.x & 63;
        int proj = wid >> 10;
        int n = wid & 1023;
        const float* W = proj == 0 ? Wk : (proj == 1 ? Wv : Wr);
        const float* m = proj == 0 ? tmk : (proj == 1 ? tmv : tmr);
        float acc[8];
#pragma unroll
        for (int bb = 0; bb < 8; bb++) acc[bb] = 0.f;
        for (int c = lane; c < 1024; c += 64) {
            float wc = W[n * 1024 + c] * (1.0f - m[c]);
#pragma unroll
            for (int bb = 0; bb < 8; bb++) acc[bb] = fmaf(lastx[bb * 1024 + c], wc, acc[bb]);
        }
#pragma unroll
        for (int bb = 0; bb < 8; bb++) {
            float v = acc[bb];
#pragma unroll
            for (int sh = 32; sh >= 1; sh >>= 1) v += __shfl_xor(v, sh);
            if (lane == 0) bias[proj * 8192 + bb * 1024 + n] = v;
        }
    }
}

// ---------------- chunked wkv scan: T=2048 = 64 chunks x 32; 2 channels/thread ----------------
__global__ __launch_bounds__(256) void wkv_pass1(
    const u16* __restrict__ Kp, const u16* __restrict__ Vp,
    const float* __restrict__ tdec,
    float* __restrict__ Ca, float* __restrict__ Cb, float* __restrict__ Ce)
{
    int tid = blockIdx.x * 256 + threadIdx.x;   // 262144 threads
    int c = (tid & 511) << 1;
    int chunk = (tid >> 9) & 63;
    int n = tid >> 15;
    float w0 = __expf(tdec[c]), w1 = __expf(tdec[c + 1]);
    int base = (n * 2048 + chunk * 32) * 1024 + c;
    float a0 = 0.f, b0 = 0.f, e0 = -1e30f;
    float a1 = 0.f, b1 = 0.f, e1 = -1e30f;
#pragma unroll 4
    for (int i = 0; i < 32; i++) {
        u32 ku = *(const u32*)(Kp + base + (i << 10));
        u32 vu = *(const u32*)(Vp + base + (i << 10));
        float k0 = b2f((u16)ku), k1 = b2f((u16)(ku >> 16));
        float v0 = b2f((u16)vu), v1 = b2f((u16)(vu >> 16));
        float en0 = fmaxf(e0 - w0, k0);
        float f10 = __expf(e0 - w0 - en0), f20 = __expf(k0 - en0);
        a0 = fmaf(f10, a0, f20 * v0); b0 = fmaf(f10, b0, f20); e0 = en0;
        float en1 = fmaxf(e1 - w1, k1);
        float f11 = __expf(e1 - w1 - en1), f21 = __expf(k1 - en1);
        a1 = fmaf(f11, a1, f21 * v1); b1 = fmaf(f11, b1, f21); e1 = en1;
    }
    int oidx = ((n * 64 + chunk) << 10) + c;
    *(float2*)(Ca + oidx) = make_float2(a0, a1);
    *(float2*)(Cb + oidx) = make_float2(b0, b1);
    *(float2*)(Ce + oidx) = make_float2(e0, e1);
}

// In-place: overwrites chunk summaries with chunk-start prefixes (read temps first).
__global__ __launch_bounds__(256) void wkv_pass2(
    const float* __restrict__ state, const float* __restrict__ tdec,
    float* Ca, float* Cb, float* Ce)
{
    int tid = blockIdx.x * 256 + threadIdx.x;   // 8192 threads
    int c = tid & 1023;
    int n = tid >> 10;
    float a = state[(n * 3 + 0) * 1024 + c];
    float b = state[(n * 3 + 1) * 1024 + c];
    float e = state[(n * 3 + 2) * 1024 + c];
    float wL = __expf(tdec[c]) * 32.0f;
    for (int ch = 0; ch < 64; ++ch) {
        int idx = ((n * 64 + ch) << 10) + c;
        float ca = Ca[idx], cb = Cb[idx], ce = Ce[idx];
        Ca[idx] = a; Cb[idx] = b; Ce[idx] = e;
        float en = fmaxf(e - wL, ce);
        float f1 = __expf(e - wL - en);
        float f2 = __expf(ce - en);
        a = fmaf(f1, a, f2 * ca);
        b = fmaf(f1, b, f2 * cb);
        e = en;
    }
}

__global__ __launch_bounds__(256) void wkv_pass3(
    const u16* __restrict__ Kp, const u16* __restrict__ Vp, const u16* __restrict__ SRp,
    const float* __restrict__ Sa, const float* __restrict__ Sb, const float* __restrict__ Se,
    const float* __restrict__ tfirst, const float* __restrict__ tdec,
    u16* __restrict__ Pp)
{
    int tid = blockIdx.x * 256 + threadIdx.x;   // 262144 threads
    int c = (tid & 511) << 1;
    int chunk = (tid >> 9) & 63;
    int n = tid >> 15;
    int sidx = ((n * 64 + chunk) << 10) + c;
    float a0 = Sa[sidx], b0 = Sb[sidx], e0 = Se[sidx];
    float a1 = Sa[sidx + 1], b1 = Sb[sidx + 1], e1 = Se[sidx + 1];
    float u0 = tfirst[c], u1 = tfirst[c + 1];
    float w0 = __expf(tdec[c]), w1 = __expf(tdec[c + 1]);
    int base = (n * 2048 + chunk * 32) * 1024 + c;
#pragma unroll 2
    for (int i = 0; i < 32; i++) {
        u32 ku = *(const u32*)(Kp + base + (i << 10));
        u32 vu = *(const u32*)(Vp + base + (i << 10));
        u32 su = *(const u32*)(SRp + base + (i << 10));
        float k0 = b2f((u16)ku), k1 = b2f((u16)(ku >> 16));
        float v0 = b2f((u16)vu), v1 = b2f((u16)(vu >> 16));
        float s0 = b2f((u16)su), s1 = b2f((u16)(su >> 16));
        float t0 = fmaxf(u0 + k0, e0);
        float x10 = __expf(e0 - t0), x20 = __expf(u0 + k0 - t0);
        float wkv0 = __fdividef(fmaf(x10, a0, x20 * v0), fmaf(x10, b0, x20));
        float t1 = fmaxf(u1 + k1, e1);
        float x11 = __expf(e1 - t1), x21 = __expf(u1 + k1 - t1);
        float wkv1 = __fdividef(fmaf(x11, a1, x21 * v1), fmaf(x11, b1, x21));
        *(u32*)(Pp + base + (i << 10)) = (u32)f2b(wkv0 * s0) | ((u32)f2b(wkv1 * s1) << 16);
        float en0 = fmaxf(e0 - w0, k0);
        float f10 = __expf(e0 - w0 - en0), f20 = __expf(k0 - en0);
        a0 = fmaf(f10, a0, f20 * v0); b0 = fmaf(f10, b0, f20); e0 = en0;
        float en1 = fmaxf(e1 - w1, k1);
        float f11 = __expf(e1 - w1 - en1), f21 = __expf(k1 - en1);
        a1 = fmaf(f11, a1, f21 * v1); b1 = fmaf(f11, b1, f21); e1 = en1;
    }
}

extern "C" void kernel_launch(void* const* d_in, const int* in_sizes, int n_in,
                              void* d_out, int out_size, void* d_ws, size_t ws_size,
                              hipStream_t stream) {
    const float* x      = (const float*)d_in[0];
    const float* Wk     = (const float*)d_in[2];
    const float* Wv     = (const float*)d_in[3];
    const float* Wr     = (const float*)d_in[4];
    const float* Wo     = (const float*)d_in[5];
    const float* tmk    = (const float*)d_in[6];
    const float* tmv    = (const float*)d_in[7];
    const float* tmr    = (const float*)d_in[8];
    const float* tdec   = (const float*)d_in[9];
    const float* tfirst = (const float*)d_in[10];
    const float* lastx  = (const float*)d_in[11];
    const float* state  = (const float*)d_in[12];
    float* out = (float*)d_out;

    const size_t MB = 1024ull * 1024ull;
    char* ws = (char*)d_ws;
    u16* Kb   = (u16*)(ws);                  // 32 MB
    u16* Vb   = (u16*)(ws + 32 * MB);        // 32 MB
    u16* SRb  = (u16*)(ws + 64 * MB);        // 32 MB
    u16* xb   = (u16*)(ws + 96 * MB);        // 32 MB; reused as P after gemm_kvr
    u16* Wall = (u16*)(ws + 128 * MB);       // 8 MB
    float* bias = (float*)(ws + 136 * MB);   // 96 KB
    float* Ca = (float*)(ws + 137 * MB);     // 2 MB each (64 chunks)
    float* Cb = (float*)(ws + 139 * MB);
    float* Ce = (float*)(ws + 141 * MB);
    u16* Pb = xb;

    dim3 blk(256);
    prep_all<<<21248, blk, 0, stream>>>(x, lastx, Wk, Wv, Wr, Wo, tmk, tmv, tmr, xb, Wall, bias);
    gemm_kvr<<<dim3(24, 128), blk, 0, stream>>>(xb, Wall, bias, Kb, Vb, SRb);
    wkv_pass1<<<1024, blk, 0, stream>>>(Kb, Vb, tdec, Ca, Cb, Ce);
    wkv_pass2<<<32, blk, 0, stream>>>(state, tdec, Ca, Cb, Ce);
    wkv_pass3<<<1024, blk, 0, stream>>>(Kb, Vb, SRb, Ca, Cb, Ce, tfirst, tdec, Pb);
    gemm_out<<<dim3(8, 128), blk, 0, stream>>>(Pb, Wall + 3145728, out);
}

// Round 5
// 368.061 us; speedup vs baseline: 1.0518x; 1.0518x over previous
//
#include <hip/hip_runtime.h>
#include <hip/hip_bf16.h>
#include <stdint.h>

// RWKV TimeMixing: N=8, T=2048, C=1024.
// Round 5: gemm_kvr restructured for A-tile reuse across the 3 projections:
// one block computes K,V,R 128x128 tiles (stage A once, 3 B panels, 48 MFMA/iter).

typedef float f4 __attribute__((ext_vector_type(4)));
typedef short bh8 __attribute__((ext_vector_type(8)));
typedef unsigned int u32;
typedef unsigned short u16;

__device__ __forceinline__ u32 cvt2bf(float a, float b) {
    __hip_bfloat162 h = __float22bfloat162_rn(make_float2(a, b));
    u32 u; __builtin_memcpy(&u, &h, 4); return u;
}
__device__ __forceinline__ float b2f(u16 u) {
    u32 x = (u32)u << 16; float f; __builtin_memcpy(&f, &x, 4); return f;
}
__device__ __forceinline__ u16 f2b(float f) {
    __hip_bfloat16 h = __float2bfloat16(f);
    u16 u; __builtin_memcpy(&u, &h, 2); return u;
}
__device__ __forceinline__ void gld_lds16(const void* g, void* l) {
    __builtin_amdgcn_global_load_lds(
        (const __attribute__((address_space(1))) u32*)g,
        (__attribute__((address_space(3))) u32*)l, 16, 0, 0);
}

// Merged K/V/R GEMM with A-reuse. grid (8, 128): bx = n-tile, by = m-tile.
// Per block: acc[3][4][4]; K-loop stages A + 3 B panels (XOR-swizzled global source,
// 0-conflict per R2/R3), 48 MFMA per BK=32 iter. Epilogue: +bias, sigmoid on proj2,
// LDS repack -> dwordx4 bf16 stores, looped over proj.
__global__ __launch_bounds__(256, 2) void gemm_kvr(
    const u16* __restrict__ A, const u16* __restrict__ Wall, const float* __restrict__ bias,
    u16* __restrict__ Kb, u16* __restrict__ Vb, u16* __restrict__ SRb)
{
    __shared__ __align__(16) char pool[33792];   // K-loop: As(8K)+3xBs(8K)=32K; epi: 128x132 u16
    u16* As = (u16*)pool;

    const int n0 = blockIdx.x * 128;
    const int m0 = blockIdx.y * 128;

    const int tid  = threadIdx.x;
    const int w    = tid >> 6;
    const int lane = tid & 63;

    // staging geometry
    const int srow = w * 32 + (lane >> 2);
    const int slot = lane & 3;
    const int chk  = slot ^ ((srow >> 1) & 3);
    const u16* gA0 = A + (size_t)(m0 + srow) * 1024 + chk * 8;
    const u16* gA1 = gA0 + (size_t)16 * 1024;
    const u16* gW0 = Wall + (size_t)(n0 + srow) * 1024 + chk * 8;   // +p*1M per proj
    const u16* gW1 = gW0 + (size_t)16 * 1024;
    u16* lA0 = As + (w * 32) * 32;
    u16* lA1 = lA0 + 16 * 32;

    // fragment geometry
    const int fr   = lane & 15;
    const int quad = lane >> 4;
    const int wm = (w & 1) * 64;
    const int wn = (w >> 1) * 64;
    const int sp = quad ^ ((fr >> 1) & 3);
    const int aoff = (wm + fr) * 32 + sp * 8;
    const int boff = (wn + fr) * 32 + sp * 8;

    f4 acc[3][4][4];
#pragma unroll
    for (int p = 0; p < 3; p++)
#pragma unroll
        for (int i = 0; i < 4; i++)
#pragma unroll
            for (int j = 0; j < 4; j++) { f4 z = {0.f, 0.f, 0.f, 0.f}; acc[p][i][j] = z; }

    for (int kk = 0; kk < 1024; kk += 32) {
        gld_lds16(gA0 + kk, lA0);
        gld_lds16(gA1 + kk, lA1);
#pragma unroll
        for (int p = 0; p < 3; p++) {
            u16* lB0 = (u16*)(pool + 8192 + p * 8192) + (w * 32) * 32;
            gld_lds16(gW0 + (size_t)p * 1048576 + kk, lB0);
            gld_lds16(gW1 + (size_t)p * 1048576 + kk, lB0 + 16 * 32);
        }
        __syncthreads();
        bh8 af[4];
#pragma unroll
        for (int i = 0; i < 4; i++) af[i] = *(const bh8*)(As + aoff + i * 16 * 32);
#pragma unroll
        for (int p = 0; p < 3; p++) {
            const u16* Bs = (const u16*)(pool + 8192 + p * 8192);
            bh8 bf[4];
#pragma unroll
            for (int j = 0; j < 4; j++) bf[j] = *(const bh8*)(Bs + boff + j * 16 * 32);
#pragma unroll
            for (int i = 0; i < 4; i++)
#pragma unroll
                for (int j = 0; j < 4; j++)
                    acc[p][i][j] = __builtin_amdgcn_mfma_f32_16x16x32_bf16(af[i], bf[j], acc[p][i][j], 0, 0, 0);
        }
        __syncthreads();
    }

    // epilogue
    const int rb = quad * 4;
    const int batch = m0 >> 11;
    u16* S = (u16*)pool;
    const int ch = lane & 15;
#pragma unroll
    for (int p = 0; p < 3; p++) {
        float bv[4];
#pragma unroll
        for (int j = 0; j < 4; j++) bv[j] = bias[p * 8192 + batch * 1024 + n0 + wn + j * 16 + fr];
        if (p) __syncthreads();                  // prior store-phase reads done
#pragma unroll
        for (int i = 0; i < 4; i++)
#pragma unroll
            for (int j = 0; j < 4; j++)
#pragma unroll
                for (int r = 0; r < 4; r++) {
                    float v = acc[p][i][j][r] + bv[j];
                    if (p == 2) v = __fdividef(1.0f, 1.0f + __expf(-v));
                    S[(wm + i * 16 + rb + r) * 132 + wn + j * 16 + fr] = f2b(v);
                }
        __syncthreads();
        u16* Y = p == 0 ? Kb : (p == 1 ? Vb : SRb);
#pragma unroll
        for (int t = 0; t < 8; t++) {
            int lrow = w * 32 + t * 4 + (lane >> 4);
            const u16* ptr = S + lrow * 132 + ch * 8;
            uint2 lo = *(const uint2*)ptr;
            uint2 hi = *(const uint2*)(ptr + 4);
            uint4 val = make_uint4(lo.x, lo.y, hi.x, hi.y);
            *(uint4*)(Y + (size_t)(m0 + lrow) * 1024 + n0 + ch * 8) = val;
        }
    }
}

// Output GEMM: out(16384,1024) f32 = P @ Wo^T. grid (8, 128). 4-pass f32 LDS repack epilogue.
__global__ __launch_bounds__(256, 4) void gemm_out(
    const u16* __restrict__ A, const u16* __restrict__ B, float* __restrict__ Y)
{
    __shared__ __align__(16) char pool[33792];
    u16* As = (u16*)pool;
    u16* Bs = (u16*)(pool + 8192);
    const int n0 = blockIdx.x * 128;
    const int m0 = blockIdx.y * 128;

    const int tid  = threadIdx.x;
    const int w    = tid >> 6;
    const int lane = tid & 63;
    const int srow = w * 32 + (lane >> 2);
    const int slot = lane & 3;
    const int chk  = slot ^ ((srow >> 1) & 3);
    const u16* gA0 = A + (size_t)(m0 + srow) * 1024 + chk * 8;
    const u16* gA1 = gA0 + (size_t)16 * 1024;
    const u16* gB0 = B + (size_t)(n0 + srow) * 1024 + chk * 8;
    const u16* gB1 = gB0 + (size_t)16 * 1024;
    u16* lA0 = As + (w * 32) * 32;
    u16* lA1 = lA0 + 16 * 32;
    u16* lB0 = Bs + (w * 32) * 32;
    u16* lB1 = lB0 + 16 * 32;

    const int fr   = lane & 15;
    const int quad = lane >> 4;
    const int wm = (w & 1) * 64;
    const int wn = (w >> 1) * 64;
    const int sp = quad ^ ((fr >> 1) & 3);
    const int aoff = (wm + fr) * 32 + sp * 8;
    const int boff = (wn + fr) * 32 + sp * 8;

    f4 acc[4][4];
#pragma unroll
    for (int i = 0; i < 4; i++)
#pragma unroll
        for (int j = 0; j < 4; j++) { f4 z = {0.f, 0.f, 0.f, 0.f}; acc[i][j] = z; }

    for (int kk = 0; kk < 1024; kk += 32) {
        gld_lds16(gA0 + kk, lA0);
        gld_lds16(gA1 + kk, lA1);
        gld_lds16(gB0 + kk, lB0);
        gld_lds16(gB1 + kk, lB1);
        __syncthreads();
        bh8 af[4], bf[4];
#pragma unroll
        for (int i = 0; i < 4; i++) af[i] = *(const bh8*)(As + aoff + i * 16 * 32);
#pragma unroll
        for (int j = 0; j < 4; j++) bf[j] = *(const bh8*)(Bs + boff + j * 16 * 32);
#pragma unroll
        for (int i = 0; i < 4; i++)
#pragma unroll
            for (int j = 0; j < 4; j++)
                acc[i][j] = __builtin_amdgcn_mfma_f32_16x16x32_bf16(af[i], bf[j], acc[i][j], 0, 0, 0);
        __syncthreads();
    }

    const int rb = quad * 4;
    float* Sf = (float*)pool;
#pragma unroll
    for (int i = 0; i < 4; i++) {
        __syncthreads();
#pragma unroll
        for (int j = 0; j < 4; j++)
#pragma unroll
            for (int r = 0; r < 4; r++) {
                int lrow = (w & 1) * 16 + rb + r;
                Sf[lrow * 132 + wn + j * 16 + fr] = acc[i][j][r];
            }
        __syncthreads();
#pragma unroll
        for (int t = 0; t < 4; t++) {
            int lrow = w * 8 + t * 2 + (lane >> 5);
            int ch = lane & 31;
            f4 val = *(const f4*)(Sf + lrow * 132 + ch * 4);
            int g = m0 + ((lrow >> 4) << 6) + i * 16 + (lrow & 15);
            *(f4*)(Y + (size_t)g * 1024 + n0 + ch * 4) = val;
        }
    }
}

// ---------------- fused prep: convx | prepw | bias3, grid-partitioned ----------------
__global__ __launch_bounds__(256) void prep_all(
    const float* __restrict__ x, const float* __restrict__ lastx,
    const float* __restrict__ Wk, const float* __restrict__ Wv,
    const float* __restrict__ Wr, const float* __restrict__ Wo,
    const float* __restrict__ tmk, const float* __restrict__ tmv, const float* __restrict__ tmr,
    u16* __restrict__ xb, u16* __restrict__ Wall, float* __restrict__ bias)
{
    int b = blockIdx.x;
    if (b < 16384) {
        int e = (b * 256 + threadIdx.x) << 2;
        f4 v = *(const f4*)(x + e);
        *(uint2*)(xb + e) = make_uint2(cvt2bf(v.x, v.y), cvt2bf(v.z, v.w));
    } else if (b < 20480) {
        int e = ((b - 16384) * 256 + threadIdx.x) << 2;
        int wid = e >> 20;
        int off = e & 1048575;
        int c = e & 1023;
        const float* src = wid == 0 ? Wk : (wid == 1 ? Wv : (wid == 2 ? Wr : Wo));
        f4 v = *(const f4*)(src + off);
        if (wid < 3) {
            const float* m = wid == 0 ? tmk : (wid == 1 ? tmv : tmr);
            v = v * *(const f4*)(m + c);
        }
        *(uint2*)(Wall + e) = make_uint2(cvt2bf(v.x, v.y), cvt2bf(v.z, v.w));
    } else {
        int wid = (b - 20480) * 4 + (threadIdx.x >> 6);
        int lane = threadIdx.x & 63;
        int proj = wid >> 10;
        int n = wid & 1023;
        const float* W = proj == 0 ? Wk : (proj == 1 ? Wv : Wr);
        const float* m = proj == 0 ? tmk : (proj == 1 ? tmv : tmr);
        float acc[8];
#pragma unroll
        for (int bb = 0; bb < 8; bb++) acc[bb] = 0.f;
        for (int c = lane; c < 1024; c += 64) {
            float wc = W[n * 1024 + c] * (1.0f - m[c]);
#pragma unroll
            for (int bb = 0; bb < 8; bb++) acc[bb] = fmaf(lastx[bb * 1024 + c], wc, acc[bb]);
        }
#pragma unroll
        for (int bb = 0; bb < 8; bb++) {
            float v = acc[bb];
#pragma unroll
            for (int sh = 32; sh >= 1; sh >>= 1) v += __shfl_xor(v, sh);
            if (lane == 0) bias[proj * 8192 + bb * 1024 + n] = v;
        }
    }
}

// ---------------- chunked wkv scan: T=2048 = 64 chunks x 32; 2 channels/thread ----------------
__global__ __launch_bounds__(256) void wkv_pass1(
    const u16* __restrict__ Kp, const u16* __restrict__ Vp,
    const float* __restrict__ tdec,
    float* __restrict__ Ca, float* __restrict__ Cb, float* __restrict__ Ce)
{
    int tid = blockIdx.x * 256 + threadIdx.x;
    int c = (tid & 511) << 1;
    int chunk = (tid >> 9) & 63;
    int n = tid >> 15;
    float w0 = __expf(tdec[c]), w1 = __expf(tdec[c + 1]);
    int base = (n * 2048 + chunk * 32) * 1024 + c;
    float a0 = 0.f, b0 = 0.f, e0 = -1e30f;
    float a1 = 0.f, b1 = 0.f, e1 = -1e30f;
#pragma unroll 4
    for (int i = 0; i < 32; i++) {
        u32 ku = *(const u32*)(Kp + base + (i << 10));
        u32 vu = *(const u32*)(Vp + base + (i << 10));
        float k0 = b2f((u16)ku), k1 = b2f((u16)(ku >> 16));
        float v0 = b2f((u16)vu), v1 = b2f((u16)(vu >> 16));
        float en0 = fmaxf(e0 - w0, k0);
        float f10 = __expf(e0 - w0 - en0), f20 = __expf(k0 - en0);
        a0 = fmaf(f10, a0, f20 * v0); b0 = fmaf(f10, b0, f20); e0 = en0;
        float en1 = fmaxf(e1 - w1, k1);
        float f11 = __expf(e1 - w1 - en1), f21 = __expf(k1 - en1);
        a1 = fmaf(f11, a1, f21 * v1); b1 = fmaf(f11, b1, f21); e1 = en1;
    }
    int oidx = ((n * 64 + chunk) << 10) + c;
    *(float2*)(Ca + oidx) = make_float2(a0, a1);
    *(float2*)(Cb + oidx) = make_float2(b0, b1);
    *(float2*)(Ce + oidx) = make_float2(e0, e1);
}

// In-place: overwrites chunk summaries with chunk-start prefixes.
__global__ __launch_bounds__(256) void wkv_pass2(
    const float* __restrict__ state, const float* __restrict__ tdec,
    float* Ca, float* Cb, float* Ce)
{
    int tid = blockIdx.x * 256 + threadIdx.x;
    int c = tid & 1023;
    int n = tid >> 10;
    float a = state[(n * 3 + 0) * 1024 + c];
    float b = state[(n * 3 + 1) * 1024 + c];
    float e = state[(n * 3 + 2) * 1024 + c];
    float wL = __expf(tdec[c]) * 32.0f;
    for (int ch = 0; ch < 64; ++ch) {
        int idx = ((n * 64 + ch) << 10) + c;
        float ca = Ca[idx], cb = Cb[idx], ce = Ce[idx];
        Ca[idx] = a; Cb[idx] = b; Ce[idx] = e;
        float en = fmaxf(e - wL, ce);
        float f1 = __expf(e - wL - en);
        float f2 = __expf(ce - en);
        a = fmaf(f1, a, f2 * ca);
        b = fmaf(f1, b, f2 * cb);
        e = en;
    }
}

__global__ __launch_bounds__(256) void wkv_pass3(
    const u16* __restrict__ Kp, const u16* __restrict__ Vp, const u16* __restrict__ SRp,
    const float* __restrict__ Sa, const float* __restrict__ Sb, const float* __restrict__ Se,
    const float* __restrict__ tfirst, const float* __restrict__ tdec,
    u16* __restrict__ Pp)
{
    int tid = blockIdx.x * 256 + threadIdx.x;
    int c = (tid & 511) << 1;
    int chunk = (tid >> 9) & 63;
    int n = tid >> 15;
    int sidx = ((n * 64 + chunk) << 10) + c;
    float a0 = Sa[sidx], b0 = Sb[sidx], e0 = Se[sidx];
    float a1 = Sa[sidx + 1], b1 = Sb[sidx + 1], e1 = Se[sidx + 1];
    float u0 = tfirst[c], u1 = tfirst[c + 1];
    float w0 = __expf(tdec[c]), w1 = __expf(tdec[c + 1]);
    int base = (n * 2048 + chunk * 32) * 1024 + c;
#pragma unroll 2
    for (int i = 0; i < 32; i++) {
        u32 ku = *(const u32*)(Kp + base + (i << 10));
        u32 vu = *(const u32*)(Vp + base + (i << 10));
        u32 su = *(const u32*)(SRp + base + (i << 10));
        float k0 = b2f((u16)ku), k1 = b2f((u16)(ku >> 16));
        float v0 = b2f((u16)vu), v1 = b2f((u16)(vu >> 16));
        float s0 = b2f((u16)su), s1 = b2f((u16)(su >> 16));
        float t0 = fmaxf(u0 + k0, e0);
        float x10 = __expf(e0 - t0), x20 = __expf(u0 + k0 - t0);
        float wkv0 = __fdividef(fmaf(x10, a0, x20 * v0), fmaf(x10, b0, x20));
        float t1 = fmaxf(u1 + k1, e1);
        float x11 = __expf(e1 - t1), x21 = __expf(u1 + k1 - t1);
        float wkv1 = __fdividef(fmaf(x11, a1, x21 * v1), fmaf(x11, b1, x21));
        *(u32*)(Pp + base + (i << 10)) = (u32)f2b(wkv0 * s0) | ((u32)f2b(wkv1 * s1) << 16);
        float en0 = fmaxf(e0 - w0, k0);
        float f10 = __expf(e0 - w0 - en0), f20 = __expf(k0 - en0);
        a0 = fmaf(f10, a0, f20 * v0); b0 = fmaf(f10, b0, f20); e0 = en0;
        float en1 = fmaxf(e1 - w1, k1);
        float f11 = __expf(e1 - w1 - en1), f21 = __expf(k1 - en1);
        a1 = fmaf(f11, a1, f21 * v1); b1 = fmaf(f11, b1, f21); e1 = en1;
    }
}

extern "C" void kernel_launch(void* const* d_in, const int* in_sizes, int n_in,
                              void* d_out, int out_size, void* d_ws, size_t ws_size,
                              hipStream_t stream) {
    const float* x      = (const float*)d_in[0];
    const float* Wk     = (const float*)d_in[2];
    const float* Wv     = (const float*)d_in[3];
    const float* Wr     = (const float*)d_in[4];
    const float* Wo     = (const float*)d_in[5];
    const float* tmk    = (const float*)d_in[6];
    const float* tmv    = (const float*)d_in[7];
    const float* tmr    = (const float*)d_in[8];
    const float* tdec   = (const float*)d_in[9];
    const float* tfirst = (const float*)d_in[10];
    const float* lastx  = (const float*)d_in[11];
    const float* state  = (const float*)d_in[12];
    float* out = (float*)d_out;

    const size_t MB = 1024ull * 1024ull;
    char* ws = (char*)d_ws;
    u16* Kb   = (u16*)(ws);                  // 32 MB
    u16* Vb   = (u16*)(ws + 32 * MB);        // 32 MB
    u16* SRb  = (u16*)(ws + 64 * MB);        // 32 MB
    u16* xb   = (u16*)(ws + 96 * MB);        // 32 MB; reused as P after gemm_kvr
    u16* Wall = (u16*)(ws + 128 * MB);       // 8 MB
    float* bias = (float*)(ws + 136 * MB);   // 96 KB
    float* Ca = (float*)(ws + 137 * MB);     // 2 MB each (64 chunks)
    float* Cb = (float*)(ws + 139 * MB);
    float* Ce = (float*)(ws + 141 * MB);
    u16* Pb = xb;

    dim3 blk(256);
    prep_all<<<21248, blk, 0, stream>>>(x, lastx, Wk, Wv, Wr, Wo, tmk, tmv, tmr, xb, Wall, bias);
    gemm_kvr<<<dim3(8, 128), blk, 0, stream>>>(xb, Wall, bias, Kb, Vb, SRb);
    wkv_pass1<<<1024, blk, 0, stream>>>(Kb, Vb, tdec, Ca, Cb, Ce);
    wkv_pass2<<<32, blk, 0, stream>>>(state, tdec, Ca, Cb, Ce);
    wkv_pass3<<<1024, blk, 0, stream>>>(Kb, Vb, SRb, Ca, Cb, Ce, tfirst, tdec, Pb);
    gemm_out<<<dim3(8, 128), blk, 0, stream>>>(Pb, Wall + 3145728, out);
}